// Round 10
// baseline (305.234 us; speedup 1.0000x reference)
//
#include <hip/hip_runtime.h>
#include <cstdint>

#define SEQ 4096
#define NH 12
#define DH 64
#define DM 768
#define MT 8192      // B*SEQ
#define QKVN 2304    // 3*DM

typedef __bf16 bf16;
typedef __attribute__((ext_vector_type(8))) __bf16 bf16x8;
typedef __attribute__((ext_vector_type(4))) __bf16 bf16x4;
typedef __attribute__((ext_vector_type(2))) __bf16 bf16x2;
typedef __attribute__((ext_vector_type(4))) float f32x4;
typedef __attribute__((ext_vector_type(16))) float f32x16;
typedef __attribute__((ext_vector_type(2))) int int2v;

// async global->LDS, 16B per lane. LDS dest is wave-uniform base + lane*16.
__device__ __forceinline__ void async_ld16(const void* g, void* lds) {
  __builtin_amdgcn_global_load_lds(
      (__attribute__((address_space(1))) void*)(void*)g,
      (__attribute__((address_space(3))) void*)lds, 16, 0, 0);
}

// Schraudolph-style exp2 emitting BF16 BITS directly, two elements packed.
// bf16(2^s) bits ~= (int)(s*128 + 16251.5); +-3.5% rel, softmax-ratio cancels
// the common mode. Integer/VALU only — never touches the trans pipe.
__device__ __forceinline__ int pexp2_pair(float s0, float s1) {
  int j0 = (int)__builtin_fmaf(s0, 128.0f, 16251.5f);
  int j1 = (int)__builtin_fmaf(s1, 128.0f, 16251.5f);
  return j0 | (j1 << 16);
}

// (a,b) -> a' = {a.lo32, b.lo32}, b' = {a.hi32, b.hi32}
__device__ __forceinline__ void lane32_swap(int& a, int& b) {
#if __has_builtin(__builtin_amdgcn_permlane32_swap)
  int2v r = __builtin_amdgcn_permlane32_swap(a, b, false, false);
  a = r.x; b = r.y;
#else
  int hi = (threadIdx.x & 63) >> 5;
  int ra = __shfl_xor(a, 32, 64), rb = __shfl_xor(b, 32, 64);
  int na = hi ? rb : a;
  int nb = hi ? b : ra;
  a = na; b = nb;
#endif
}

// ---------------------------------------------------------------- converts (merged)
#define NX4  (MT * DM / 4)
#define NW14 (QKVN * DM / 4)
#define NW24 (DM * DM / 4)
__global__ void cvt_all(const float* __restrict__ x, const float* __restrict__ w1,
                        const float* __restrict__ w2, bf16* __restrict__ xb,
                        bf16* __restrict__ wb1, bf16* __restrict__ wb2) {
  int i = blockIdx.x * blockDim.x + threadIdx.x;
  const float* src; bf16* dst; int j;
  if (i < NX4) { src = x; dst = xb; j = i; }
  else if (i < NX4 + NW14) { src = w1; dst = wb1; j = i - NX4; }
  else if (i < NX4 + NW14 + NW24) { src = w2; dst = wb2; j = i - NX4 - NW14; }
  else return;
  f32x4 v = ((const f32x4*)src)[j];
  bf16x4 o;
  o.x = (bf16)v.x; o.y = (bf16)v.y; o.z = (bf16)v.z; o.w = (bf16)v.w;
  ((bf16x4*)dst)[j] = o;
}

// ---------------------------------------------------------------- GEMM (B^T)
// C[M,N] = A[M,K] @ Bw[N,K]^T. 128x128 tile, BK=32, 4 waves, 64x64/wave.
// 1-D grid with grouped swizzle: groups of 8 m-tiles sweep all n-tiles, so B is
// re-read 8x (not 64x) from L2/L3 and per-XCD working sets fit L2.
// MODE 0: QKV epilogue -> +bias, Q(*0.125*log2e)/K as [bh][n][d]; V^T via LDS -> [bh][d][n]
// MODE 1: out-proj epilogue -> +bias, fp32 row-major [M,N]
template<int MODE>
__global__ __launch_bounds__(256) void gemm_bt(
    const bf16* __restrict__ A, const bf16* __restrict__ Bw,
    const float* __restrict__ bias,
    bf16* __restrict__ outQ, bf16* __restrict__ outK, bf16* __restrict__ outVt,
    float* __restrict__ outF,
    int M, int N, int K)
{
  __shared__ bf16 sA[128 * 32];
  __shared__ bf16 sB[128 * 32];
  __shared__ bf16 sT[MODE == 0 ? 64 * 136 : 1];   // V^T bounce buffer
  const int tid  = threadIdx.x;
  const int wave = tid >> 6;
  const int lane = tid & 63;
  const int l15  = lane & 15;
  const int quad = lane >> 4;

  // grouped swizzle: lin -> (m_tile, n_tile); within a group of 8 m-tiles the
  // n-tiles vary second-fastest so consecutive blocks (-> different XCDs) share n.
  constexpr int NT = (MODE == 0) ? (QKVN / 128) : (DM / 128);
  const int lin = blockIdx.x;
  const int rem = lin % (NT * 8);
  const int m0 = ((lin / (NT * 8)) * 8 + (rem % 8)) * 128;
  const int n0 = (rem / 8) * 128;

  const int rowbase = (wave >> 1) * 64;
  const int colbase = (wave & 1) * 64;

  f32x4 acc[4][4] = {};

  const int sr = lane >> 2;
  const int sc = (lane & 3) * 8;

  for (int kt = 0; kt < K; kt += 32) {
#pragma unroll
    for (int p = 0; p < 4; ++p) {
      int chunk = p * 4 + wave;
      int r = (chunk & 7) * 16 + sr;
      if (chunk < 8) {
        async_ld16(A + (size_t)(m0 + r) * K + kt + sc, &sA[(chunk & 7) * 512]);
      } else {
        async_ld16(Bw + (size_t)(n0 + r) * K + kt + sc, &sB[(chunk & 7) * 512]);
      }
    }
    __syncthreads();

    bf16x8 af[4], bfr[4];
#pragma unroll
    for (int rt = 0; rt < 4; ++rt)
      af[rt] = *(const bf16x8*)&sA[(rowbase + rt * 16 + l15) * 32 + quad * 8];
#pragma unroll
    for (int ct = 0; ct < 4; ++ct)
      bfr[ct] = *(const bf16x8*)&sB[(colbase + ct * 16 + l15) * 32 + quad * 8];
#pragma unroll
    for (int rt = 0; rt < 4; ++rt)
#pragma unroll
      for (int ct = 0; ct < 4; ++ct)
        acc[rt][ct] = __builtin_amdgcn_mfma_f32_16x16x32_bf16(af[rt], bfr[ct], acc[rt][ct], 0, 0, 0);
    __syncthreads();
  }

  if (MODE == 0) {
    const int g = n0 / DM;                       // uniform per block (0=q,1=k,2=v)
    if (g < 2) {
      const float qscale = 0.125f * 1.4426950408889634f;  // fold /8 and log2(e) for exp2
#pragma unroll
      for (int ct = 0; ct < 4; ++ct) {
        int j = n0 + colbase + ct * 16 + l15;
        float bj = bias[j];
        int f = j % DM;
        int h = f >> 6, d = f & 63;
#pragma unroll
        for (int rt = 0; rt < 4; ++rt) {
          int mrow = m0 + rowbase + rt * 16 + quad * 4;
#pragma unroll
          for (int r = 0; r < 4; ++r) {
            float v = acc[rt][ct][r] + bj;
            int m = mrow + r;
            int b = m >> 12, n = m & 4095;
            int bh = b * NH + h;
            if (g == 0) outQ[((size_t)bh * SEQ + n) * DH + d] = (bf16)(v * qscale);
            else        outK[((size_t)bh * SEQ + n) * DH + d] = (bf16)v;
          }
        }
      }
    } else {
      // V block: bounce through LDS, store V^T coalesced along n
      const int f0 = n0 - 2 * DM;                // d-col base in [0,768)
      const int b = m0 >> 12, n0m = m0 & 4095;
#pragma unroll
      for (int p = 0; p < 2; ++p) {
        __syncthreads();
        if (colbase == p * 64) {
#pragma unroll
          for (int ct = 0; ct < 4; ++ct) {
            int jl = ct * 16 + l15;              // 0..63 within half
            float bj = bias[n0 + p * 64 + jl];
#pragma unroll
            for (int rt = 0; rt < 4; ++rt) {
              int ml = rowbase + rt * 16 + quad * 4;
#pragma unroll
              for (int r = 0; r < 4; ++r)
                sT[jl * 136 + ml + r] = (bf16)(acc[rt][ct][r] + bj);
            }
          }
        }
        __syncthreads();
#pragma unroll
        for (int p2 = 0; p2 < 4; ++p2) {
          int slot = p2 * 256 + tid;             // 64 j-rows x 16 m-chunks
          int jr = slot >> 4, mc = (slot & 15) * 8;
          int fj = f0 + p * 64 + jr;
          int h = fj >> 6, d = fj & 63;
          *(bf16x8*)&outVt[((size_t)(b * NH + h) * DH + d) * SEQ + n0m + mc] =
              *(const bf16x8*)&sT[jr * 136 + mc];
        }
      }
    }
  } else {
#pragma unroll
    for (int ct = 0; ct < 4; ++ct) {
      int j = n0 + colbase + ct * 16 + l15;
      float bj = bias[j];
#pragma unroll
      for (int rt = 0; rt < 4; ++rt) {
        int mrow = m0 + rowbase + rt * 16 + quad * 4;
#pragma unroll
        for (int r = 0; r < 4; ++r)
          outF[(size_t)(mrow + r) * N + j] = acc[rt][ct][r] + bj;
      }
    }
  }
}

// ---------------------------------------------------------------- flash attention v10
// = R9 + explicit software pipeline: both kb S-MFMA chains hoisted ahead of all
// exp/PV so the in-order wave can issue exp (VALU) while PV/S MFMAs drain, and
// waves de-phase less (R9: MFMA-busy 58us + VALU-busy 61us ~= 125us total ->
// pipes were serialized).
__global__ __launch_bounds__(256) void flash_attn(
    const bf16* __restrict__ Q, const bf16* __restrict__ Kg,
    const bf16* __restrict__ Vt, bf16* __restrict__ Oout)
{
  __shared__ bf16 sK[2][64 * 64];    // [key][d], granule-swizzled
  __shared__ bf16 sV[2][64 * 64];    // [d][key], granule-swizzled

  const int tid  = threadIdx.x;
  const int wave = tid >> 6;
  const int lane = tid & 63;
  const int l31  = lane & 31;
  const int hi   = lane >> 5;
  const int bh = blockIdx.y;
  const int q0w = blockIdx.x * 128 + wave * 32;

  const bf16* Qb = Q  + (size_t)bh * SEQ * DH;
  const bf16* Kb = Kg + (size_t)bh * SEQ * DH;
  const bf16* Vb = Vt + (size_t)bh * DH * SEQ;

  const int srow = lane >> 3;        // staging: row within 8-row chunk
  const int spg  = lane & 7;         // staging: physical granule (16B) within row

  // Q B-fragments; 16 VGPRs, live whole kernel
  bf16x8 qf[4];
#pragma unroll
  for (int dc = 0; dc < 4; ++dc)
    qf[dc] = *(const bf16x8*)&Qb[(size_t)(q0w + l31) * DH + dc * 16 + hi * 8];

  // ones B-fragment for row-sum MFMA
  bf16x8 ones1;
#pragma unroll
  for (int j = 0; j < 8; ++j) ones1[j] = (bf16)1.0f;

  f32x16 o0 = {}, o1 = {}, o2 = {};
  f32x16 zc = {};                    // persistent zero C operand (never written)

  // hoisted LDS element offsets (kt-invariant); 2-D swizzle key
  const int keyk = (l31 & 7) ^ (((l31 >> 3) & 3) << 1);
  int kOff[4], vOff[4];
#pragma unroll
  for (int dc = 0; dc < 4; ++dc)
    kOff[dc] = l31 * 64 + (((dc * 2 + hi) ^ keyk) * 8);
#pragma unroll
  for (int k4 = 0; k4 < 4; ++k4)     // k4 = kb*2+kc
    vOff[k4] = l31 * 64 + (((k4 * 2 + hi) ^ keyk) * 8);

  auto stage = [&](int kt, int buf) {
#pragma unroll
    for (int j = 0; j < 2; ++j) {
      int r0 = wave * 16 + j * 8;
      int row = r0 + srow;
      int lg = spg ^ (row & 7) ^ (((row >> 3) & 3) << 1);
      async_ld16(Kb + (size_t)(kt + row) * DH + lg * 8, &sK[buf][r0 * 64]);
      async_ld16(Vb + (size_t)row * SEQ + kt + lg * 8, &sV[buf][r0 * 64]);
    }
  };

  auto compute = [&](const bf16* sKp, const bf16* sVp) {
    // phase 1: BOTH S chains (pure MFMA)
    f32x16 s0, s1;
    {
      bf16x8 kf = *(const bf16x8*)&sKp[kOff[0]];
      s0 = __builtin_amdgcn_mfma_f32_32x32x16_bf16(kf, qf[0], zc, 0, 0, 0);
    }
#pragma unroll
    for (int dc = 1; dc < 4; ++dc) {
      bf16x8 kf = *(const bf16x8*)&sKp[kOff[dc]];
      s0 = __builtin_amdgcn_mfma_f32_32x32x16_bf16(kf, qf[dc], s0, 0, 0, 0);
    }
    {
      bf16x8 kf = *(const bf16x8*)&sKp[kOff[0] + 2048];
      s1 = __builtin_amdgcn_mfma_f32_32x32x16_bf16(kf, qf[0], zc, 0, 0, 0);
    }
#pragma unroll
    for (int dc = 1; dc < 4; ++dc) {
      bf16x8 kf = *(const bf16x8*)&sKp[kOff[dc] + 2048];
      s1 = __builtin_amdgcn_mfma_f32_32x32x16_bf16(kf, qf[dc], s1, 0, 0, 0);
    }
    // phase 2: exp kb0 (VALU) -> PV kb0 (MFMA) with exp kb1 (VALU) interleavable
    union { int i[4]; bf16x8 v; } A00, A01, A10, A11;
    {
      int g0a = pexp2_pair(s0[0], s0[1]);
      int g0b = pexp2_pair(s0[2], s0[3]);
      int g1a = pexp2_pair(s0[4], s0[5]);
      int g1b = pexp2_pair(s0[6], s0[7]);
      lane32_swap(g0a, g1a); lane32_swap(g0b, g1b);
      A00.i[0] = g0a; A00.i[1] = g0b; A00.i[2] = g1a; A00.i[3] = g1b;
      g0a = pexp2_pair(s0[8], s0[9]);
      g0b = pexp2_pair(s0[10], s0[11]);
      g1a = pexp2_pair(s0[12], s0[13]);
      g1b = pexp2_pair(s0[14], s0[15]);
      lane32_swap(g0a, g1a); lane32_swap(g0b, g1b);
      A01.i[0] = g0a; A01.i[1] = g0b; A01.i[2] = g1a; A01.i[3] = g1b;
    }
    {
      bf16x8 vf0 = *(const bf16x8*)&sVp[vOff[0]];
      bf16x8 vf1 = *(const bf16x8*)&sVp[vOff[0] + 2048];
      o0 = __builtin_amdgcn_mfma_f32_32x32x16_bf16(A00.v, vf0, o0, 0, 0, 0);
      o1 = __builtin_amdgcn_mfma_f32_32x32x16_bf16(A00.v, vf1, o1, 0, 0, 0);
      o2 = __builtin_amdgcn_mfma_f32_32x32x16_bf16(A00.v, ones1, o2, 0, 0, 0);
    }
    {
      int g0a = pexp2_pair(s1[0], s1[1]);
      int g0b = pexp2_pair(s1[2], s1[3]);
      int g1a = pexp2_pair(s1[4], s1[5]);
      int g1b = pexp2_pair(s1[6], s1[7]);
      lane32_swap(g0a, g1a); lane32_swap(g0b, g1b);
      A10.i[0] = g0a; A10.i[1] = g0b; A10.i[2] = g1a; A10.i[3] = g1b;
      g0a = pexp2_pair(s1[8], s1[9]);
      g0b = pexp2_pair(s1[10], s1[11]);
      g1a = pexp2_pair(s1[12], s1[13]);
      g1b = pexp2_pair(s1[14], s1[15]);
      lane32_swap(g0a, g1a); lane32_swap(g0b, g1b);
      A11.i[0] = g0a; A11.i[1] = g0b; A11.i[2] = g1a; A11.i[3] = g1b;
    }
    {
      bf16x8 vf0 = *(const bf16x8*)&sVp[vOff[1]];
      bf16x8 vf1 = *(const bf16x8*)&sVp[vOff[1] + 2048];
      o0 = __builtin_amdgcn_mfma_f32_32x32x16_bf16(A01.v, vf0, o0, 0, 0, 0);
      o1 = __builtin_amdgcn_mfma_f32_32x32x16_bf16(A01.v, vf1, o1, 0, 0, 0);
      o2 = __builtin_amdgcn_mfma_f32_32x32x16_bf16(A01.v, ones1, o2, 0, 0, 0);
    }
    {
      bf16x8 vf0 = *(const bf16x8*)&sVp[vOff[2]];
      bf16x8 vf1 = *(const bf16x8*)&sVp[vOff[2] + 2048];
      o0 = __builtin_amdgcn_mfma_f32_32x32x16_bf16(A10.v, vf0, o0, 0, 0, 0);
      o1 = __builtin_amdgcn_mfma_f32_32x32x16_bf16(A10.v, vf1, o1, 0, 0, 0);
      o2 = __builtin_amdgcn_mfma_f32_32x32x16_bf16(A10.v, ones1, o2, 0, 0, 0);
    }
    {
      bf16x8 vf0 = *(const bf16x8*)&sVp[vOff[3]];
      bf16x8 vf1 = *(const bf16x8*)&sVp[vOff[3] + 2048];
      o0 = __builtin_amdgcn_mfma_f32_32x32x16_bf16(A11.v, vf0, o0, 0, 0, 0);
      o1 = __builtin_amdgcn_mfma_f32_32x32x16_bf16(A11.v, vf1, o1, 0, 0, 0);
      o2 = __builtin_amdgcn_mfma_f32_32x32x16_bf16(A11.v, ones1, o2, 0, 0, 0);
    }
  };

  stage(0, 0);
  __syncthreads();

  for (int kt = 0; kt < SEQ; kt += 128) {
    if (kt + 64 < SEQ) stage(kt + 64, 1);
    compute(sK[0], sV[0]);
    __syncthreads();
    if (kt + 128 < SEQ) stage(kt + 128, 0);
    compute(sK[1], sV[1]);
    __syncthreads();
  }

  // epilogue: o2[i] is the softmax denominator for exactly o0[i]/o1[i]'s row
  const int bg = bh / NH, h = bh % NH;
#pragma unroll
  for (int i = 0; i < 16; ++i) {
    int ql = 8 * (i >> 2) + (i & 3) + 4 * hi;
    float inv = 1.0f / o2[i];
    size_t base = (size_t)(bg * SEQ + q0w + ql) * DM + h * DH;
    Oout[base + l31]      = (bf16)(o0[i] * inv);
    Oout[base + 32 + l31] = (bf16)(o1[i] * inv);
  }
}

// ---------------------------------------------------------------- launcher
extern "C" void kernel_launch(void* const* d_in, const int* in_sizes, int n_in,
                              void* d_out, int out_size, void* d_ws, size_t ws_size,
                              hipStream_t stream) {
  const float* x     = (const float*)d_in[0];
  const float* qkv_w = (const float*)d_in[1];
  const float* qkv_b = (const float*)d_in[2];
  const float* out_w = (const float*)d_in[3];
  const float* out_b = (const float*)d_in[4];
  float* out = (float*)d_out;

  char* w = (char*)d_ws;
  bf16* xb    = (bf16*)w; w += (size_t)MT * DM * 2;
  bf16* wqkv  = (bf16*)w; w += (size_t)QKVN * DM * 2;
  bf16* wout  = (bf16*)w; w += (size_t)DM * DM * 2;
  bf16* Qw    = (bf16*)w; w += (size_t)MT * DM * 2;        // [bh][n][d], scaled 0.125*log2e
  bf16* Kw    = (bf16*)w; w += (size_t)MT * DM * 2;        // [bh][n][d]
  bf16* Vtw   = (bf16*)w; w += (size_t)MT * DM * 2;        // [bh][d][n]
  bf16* attnV = (bf16*)w; w += (size_t)MT * DM * 2;        // [m][768]

  const int tot4 = NX4 + NW14 + NW24;
  cvt_all<<<dim3((tot4 + 255) / 256), 256, 0, stream>>>(x, qkv_w, out_w, xb, wqkv, wout);

  gemm_bt<0><<<dim3((QKVN / 128) * (MT / 128)), 256, 0, stream>>>(
      xb, wqkv, qkv_b, Qw, Kw, Vtw, nullptr, MT, QKVN, DM);

  flash_attn<<<dim3(SEQ / 128, 2 * NH), 256, 0, stream>>>(Qw, Kw, Vtw, attnV);

  gemm_bt<1><<<dim3((DM / 128) * (MT / 128)), 256, 0, stream>>>(
      attnV, wout, out_b, nullptr, nullptr, nullptr, out, MT, DM, DM);
}

// Round 11
// 300.489 us; speedup vs baseline: 1.0158x; 1.0158x over previous
//
#include <hip/hip_runtime.h>
#include <cstdint>

#define SEQ 4096
#define NH 12
#define DH 64
#define DM 768
#define MT 8192      // B*SEQ
#define QKVN 2304    // 3*DM

typedef __bf16 bf16;
typedef __attribute__((ext_vector_type(8))) __bf16 bf16x8;
typedef __attribute__((ext_vector_type(4))) __bf16 bf16x4;
typedef __attribute__((ext_vector_type(2))) __bf16 bf16x2;
typedef __attribute__((ext_vector_type(4))) float f32x4;
typedef __attribute__((ext_vector_type(16))) float f32x16;
typedef __attribute__((ext_vector_type(2))) int int2v;

// async global->LDS, 16B per lane. LDS dest is wave-uniform base + lane*16.
__device__ __forceinline__ void async_ld16(const void* g, void* lds) {
  __builtin_amdgcn_global_load_lds(
      (__attribute__((address_space(1))) void*)(void*)g,
      (__attribute__((address_space(3))) void*)lds, 16, 0, 0);
}

// Schraudolph-style exp2 emitting BF16 BITS directly, two elements packed.
// bf16(2^s) bits ~= (int)(s*128 + 16251.5); +-3.5% rel, softmax-ratio cancels
// the common mode. Integer/VALU only — never touches the trans pipe.
__device__ __forceinline__ int pexp2_pair(float s0, float s1) {
  int j0 = (int)__builtin_fmaf(s0, 128.0f, 16251.5f);
  int j1 = (int)__builtin_fmaf(s1, 128.0f, 16251.5f);
  return j0 | (j1 << 16);
}

// (a,b) -> a' = {a.lo32, b.lo32}, b' = {a.hi32, b.hi32}
__device__ __forceinline__ void lane32_swap(int& a, int& b) {
#if __has_builtin(__builtin_amdgcn_permlane32_swap)
  int2v r = __builtin_amdgcn_permlane32_swap(a, b, false, false);
  a = r.x; b = r.y;
#else
  int hi = (threadIdx.x & 63) >> 5;
  int ra = __shfl_xor(a, 32, 64), rb = __shfl_xor(b, 32, 64);
  int na = hi ? rb : a;
  int nb = hi ? b : ra;
  a = na; b = nb;
#endif
}

// ---------------------------------------------------------------- converts (merged)
#define NX4  (MT * DM / 4)
#define NW14 (QKVN * DM / 4)
#define NW24 (DM * DM / 4)
__global__ void cvt_all(const float* __restrict__ x, const float* __restrict__ w1,
                        const float* __restrict__ w2, bf16* __restrict__ xb,
                        bf16* __restrict__ wb1, bf16* __restrict__ wb2) {
  int i = blockIdx.x * blockDim.x + threadIdx.x;
  const float* src; bf16* dst; int j;
  if (i < NX4) { src = x; dst = xb; j = i; }
  else if (i < NX4 + NW14) { src = w1; dst = wb1; j = i - NX4; }
  else if (i < NX4 + NW14 + NW24) { src = w2; dst = wb2; j = i - NX4 - NW14; }
  else return;
  f32x4 v = ((const f32x4*)src)[j];
  bf16x4 o;
  o.x = (bf16)v.x; o.y = (bf16)v.y; o.z = (bf16)v.z; o.w = (bf16)v.w;
  ((bf16x4*)dst)[j] = o;
}

// ---------------------------------------------------------------- GEMM (B^T)
// C[M,N] = A[M,K] @ Bw[N,K]^T. 128x128 tile, BK=32, 4 waves, 64x64/wave.
// 1-D grid with grouped swizzle (R10-verified: non-flash 162 -> 146.5 us).
// MODE 0: QKV epilogue -> +bias, Q(*0.125*log2e)/K as [bh][n][d]; V^T via LDS -> [bh][d][n]
// MODE 1: out-proj epilogue -> +bias, fp32 row-major [M,N]
template<int MODE>
__global__ __launch_bounds__(256) void gemm_bt(
    const bf16* __restrict__ A, const bf16* __restrict__ Bw,
    const float* __restrict__ bias,
    bf16* __restrict__ outQ, bf16* __restrict__ outK, bf16* __restrict__ outVt,
    float* __restrict__ outF,
    int M, int N, int K)
{
  __shared__ bf16 sA[128 * 32];
  __shared__ bf16 sB[128 * 32];
  __shared__ bf16 sT[MODE == 0 ? 64 * 136 : 1];   // V^T bounce buffer
  const int tid  = threadIdx.x;
  const int wave = tid >> 6;
  const int lane = tid & 63;
  const int l15  = lane & 15;
  const int quad = lane >> 4;

  constexpr int NT = (MODE == 0) ? (QKVN / 128) : (DM / 128);
  const int lin = blockIdx.x;
  const int rem = lin % (NT * 8);
  const int m0 = ((lin / (NT * 8)) * 8 + (rem % 8)) * 128;
  const int n0 = (rem / 8) * 128;

  const int rowbase = (wave >> 1) * 64;
  const int colbase = (wave & 1) * 64;

  f32x4 acc[4][4] = {};

  const int sr = lane >> 2;
  const int sc = (lane & 3) * 8;

  for (int kt = 0; kt < K; kt += 32) {
#pragma unroll
    for (int p = 0; p < 4; ++p) {
      int chunk = p * 4 + wave;
      int r = (chunk & 7) * 16 + sr;
      if (chunk < 8) {
        async_ld16(A + (size_t)(m0 + r) * K + kt + sc, &sA[(chunk & 7) * 512]);
      } else {
        async_ld16(Bw + (size_t)(n0 + r) * K + kt + sc, &sB[(chunk & 7) * 512]);
      }
    }
    __syncthreads();

    bf16x8 af[4], bfr[4];
#pragma unroll
    for (int rt = 0; rt < 4; ++rt)
      af[rt] = *(const bf16x8*)&sA[(rowbase + rt * 16 + l15) * 32 + quad * 8];
#pragma unroll
    for (int ct = 0; ct < 4; ++ct)
      bfr[ct] = *(const bf16x8*)&sB[(colbase + ct * 16 + l15) * 32 + quad * 8];
#pragma unroll
    for (int rt = 0; rt < 4; ++rt)
#pragma unroll
      for (int ct = 0; ct < 4; ++ct)
        acc[rt][ct] = __builtin_amdgcn_mfma_f32_16x16x32_bf16(af[rt], bfr[ct], acc[rt][ct], 0, 0, 0);
    __syncthreads();
  }

  if (MODE == 0) {
    const int g = n0 / DM;                       // uniform per block (0=q,1=k,2=v)
    if (g < 2) {
      const float qscale = 0.125f * 1.4426950408889634f;  // fold /8 and log2(e) for exp2
#pragma unroll
      for (int ct = 0; ct < 4; ++ct) {
        int j = n0 + colbase + ct * 16 + l15;
        float bj = bias[j];
        int f = j % DM;
        int h = f >> 6, d = f & 63;
#pragma unroll
        for (int rt = 0; rt < 4; ++rt) {
          int mrow = m0 + rowbase + rt * 16 + quad * 4;
#pragma unroll
          for (int r = 0; r < 4; ++r) {
            float v = acc[rt][ct][r] + bj;
            int m = mrow + r;
            int b = m >> 12, n = m & 4095;
            int bh = b * NH + h;
            if (g == 0) outQ[((size_t)bh * SEQ + n) * DH + d] = (bf16)(v * qscale);
            else        outK[((size_t)bh * SEQ + n) * DH + d] = (bf16)v;
          }
        }
      }
    } else {
      // V block: bounce through LDS, store V^T coalesced along n
      const int f0 = n0 - 2 * DM;                // d-col base in [0,768)
      const int b = m0 >> 12, n0m = m0 & 4095;
#pragma unroll
      for (int p = 0; p < 2; ++p) {
        __syncthreads();
        if (colbase == p * 64) {
#pragma unroll
          for (int ct = 0; ct < 4; ++ct) {
            int jl = ct * 16 + l15;              // 0..63 within half
            float bj = bias[n0 + p * 64 + jl];
#pragma unroll
            for (int rt = 0; rt < 4; ++rt) {
              int ml = rowbase + rt * 16 + quad * 4;
#pragma unroll
              for (int r = 0; r < 4; ++r)
                sT[jl * 136 + ml + r] = (bf16)(acc[rt][ct][r] + bj);
            }
          }
        }
        __syncthreads();
#pragma unroll
        for (int p2 = 0; p2 < 4; ++p2) {
          int slot = p2 * 256 + tid;             // 64 j-rows x 16 m-chunks
          int jr = slot >> 4, mc = (slot & 15) * 8;
          int fj = f0 + p * 64 + jr;
          int h = fj >> 6, d = fj & 63;
          *(bf16x8*)&outVt[((size_t)(b * NH + h) * DH + d) * SEQ + n0m + mc] =
              *(const bf16x8*)&sT[jr * 136 + mc];
        }
      }
    }
  } else {
#pragma unroll
    for (int ct = 0; ct < 4; ++ct) {
      int j = n0 + colbase + ct * 16 + l15;
      float bj = bias[j];
#pragma unroll
      for (int rt = 0; rt < 4; ++rt) {
        int mrow = m0 + rowbase + rt * 16 + quad * 4;
#pragma unroll
        for (int r = 0; r < 4; ++r)
          outF[(size_t)(mrow + r) * N + j] = acc[rt][ct][r] + bj;
      }
    }
  }
}

// ---------------------------------------------------------------- flash attention v11
// Lean pipeline: both S chains issue first (8 MFMA); then pack+PV per kc with ONE
// live A union. exp(s0) overlaps s1's MFMA execution; each pack overlaps preceding
// PV MFMAs. Extra live state vs R9 is only s1 (16 regs) — R10's four live A unions
// crossed the register cliff (occupancy 27->17%, both pipes idle). If occupancy
// drops below ~20% again, revert to R9 per-kb order.
__global__ __launch_bounds__(256) void flash_attn(
    const bf16* __restrict__ Q, const bf16* __restrict__ Kg,
    const bf16* __restrict__ Vt, bf16* __restrict__ Oout)
{
  __shared__ bf16 sK[2][64 * 64];    // [key][d], granule-swizzled
  __shared__ bf16 sV[2][64 * 64];    // [d][key], granule-swizzled

  const int tid  = threadIdx.x;
  const int wave = tid >> 6;
  const int lane = tid & 63;
  const int l31  = lane & 31;
  const int hi   = lane >> 5;
  const int bh = blockIdx.y;
  const int q0w = blockIdx.x * 128 + wave * 32;

  const bf16* Qb = Q  + (size_t)bh * SEQ * DH;
  const bf16* Kb = Kg + (size_t)bh * SEQ * DH;
  const bf16* Vb = Vt + (size_t)bh * DH * SEQ;

  const int srow = lane >> 3;        // staging: row within 8-row chunk
  const int spg  = lane & 7;         // staging: physical granule (16B) within row

  // Q B-fragments; 16 VGPRs, live whole kernel
  bf16x8 qf[4];
#pragma unroll
  for (int dc = 0; dc < 4; ++dc)
    qf[dc] = *(const bf16x8*)&Qb[(size_t)(q0w + l31) * DH + dc * 16 + hi * 8];

  // ones B-fragment for row-sum MFMA
  bf16x8 ones1;
#pragma unroll
  for (int j = 0; j < 8; ++j) ones1[j] = (bf16)1.0f;

  f32x16 o0 = {}, o1 = {}, o2 = {};
  f32x16 zc = {};                    // persistent zero C operand (never written)

  // hoisted LDS element offsets (kt-invariant); 2-D swizzle key
  const int keyk = (l31 & 7) ^ (((l31 >> 3) & 3) << 1);
  int kOff[4], vOff[4];
#pragma unroll
  for (int dc = 0; dc < 4; ++dc)
    kOff[dc] = l31 * 64 + (((dc * 2 + hi) ^ keyk) * 8);
#pragma unroll
  for (int k4 = 0; k4 < 4; ++k4)     // k4 = kb*2+kc
    vOff[k4] = l31 * 64 + (((k4 * 2 + hi) ^ keyk) * 8);

  auto stage = [&](int kt, int buf) {
#pragma unroll
    for (int j = 0; j < 2; ++j) {
      int r0 = wave * 16 + j * 8;
      int row = r0 + srow;
      int lg = spg ^ (row & 7) ^ (((row >> 3) & 3) << 1);
      async_ld16(Kb + (size_t)(kt + row) * DH + lg * 8, &sK[buf][r0 * 64]);
      async_ld16(Vb + (size_t)row * SEQ + kt + lg * 8, &sV[buf][r0 * 64]);
    }
  };

  // one pack+PV step: consumes 8 floats of s (half = 0 lo / 1 hi), V granule k4
  auto pv_step = [&](const f32x16& s, int half, const bf16* sVp, int k4) {
    int g0a = pexp2_pair(s[8 * half + 0], s[8 * half + 1]);
    int g0b = pexp2_pair(s[8 * half + 2], s[8 * half + 3]);
    int g1a = pexp2_pair(s[8 * half + 4], s[8 * half + 5]);
    int g1b = pexp2_pair(s[8 * half + 6], s[8 * half + 7]);
    lane32_swap(g0a, g1a);
    lane32_swap(g0b, g1b);
    union { int i[4]; bf16x8 v; } Af;
    Af.i[0] = g0a; Af.i[1] = g0b; Af.i[2] = g1a; Af.i[3] = g1b;
    bf16x8 vf0 = *(const bf16x8*)&sVp[vOff[k4]];
    bf16x8 vf1 = *(const bf16x8*)&sVp[vOff[k4] + 2048];
    o0 = __builtin_amdgcn_mfma_f32_32x32x16_bf16(Af.v, vf0, o0, 0, 0, 0);
    o1 = __builtin_amdgcn_mfma_f32_32x32x16_bf16(Af.v, vf1, o1, 0, 0, 0);
    o2 = __builtin_amdgcn_mfma_f32_32x32x16_bf16(Af.v, ones1, o2, 0, 0, 0);
  };

  auto compute = [&](const bf16* sKp, const bf16* sVp) {
    // phase 1: both S chains, pure MFMA issue
    f32x16 s0, s1;
    {
      bf16x8 kf = *(const bf16x8*)&sKp[kOff[0]];
      s0 = __builtin_amdgcn_mfma_f32_32x32x16_bf16(kf, qf[0], zc, 0, 0, 0);
    }
#pragma unroll
    for (int dc = 1; dc < 4; ++dc) {
      bf16x8 kf = *(const bf16x8*)&sKp[kOff[dc]];
      s0 = __builtin_amdgcn_mfma_f32_32x32x16_bf16(kf, qf[dc], s0, 0, 0, 0);
    }
    {
      bf16x8 kf = *(const bf16x8*)&sKp[kOff[0] + 2048];
      s1 = __builtin_amdgcn_mfma_f32_32x32x16_bf16(kf, qf[0], zc, 0, 0, 0);
    }
#pragma unroll
    for (int dc = 1; dc < 4; ++dc) {
      bf16x8 kf = *(const bf16x8*)&sKp[kOff[dc] + 2048];
      s1 = __builtin_amdgcn_mfma_f32_32x32x16_bf16(kf, qf[dc], s1, 0, 0, 0);
    }
    // phase 2: pack+PV per kc, one A live at a time; exp(s0) overlaps s1's
    // MFMA execution, each pack overlaps the previous 3 PV MFMAs.
    pv_step(s0, 0, sVp, 0);
    pv_step(s0, 1, sVp, 1);
    pv_step(s1, 0, sVp, 2);
    pv_step(s1, 1, sVp, 3);
  };

  stage(0, 0);
  __syncthreads();

  for (int kt = 0; kt < SEQ; kt += 128) {
    if (kt + 64 < SEQ) stage(kt + 64, 1);
    compute(sK[0], sV[0]);
    __syncthreads();
    if (kt + 128 < SEQ) stage(kt + 128, 0);
    compute(sK[1], sV[1]);
    __syncthreads();
  }

  // epilogue: o2[i] is the softmax denominator for exactly o0[i]/o1[i]'s row
  const int bg = bh / NH, h = bh % NH;
#pragma unroll
  for (int i = 0; i < 16; ++i) {
    int ql = 8 * (i >> 2) + (i & 3) + 4 * hi;
    float inv = 1.0f / o2[i];
    size_t base = (size_t)(bg * SEQ + q0w + ql) * DM + h * DH;
    Oout[base + l31]      = (bf16)(o0[i] * inv);
    Oout[base + 32 + l31] = (bf16)(o1[i] * inv);
  }
}

// ---------------------------------------------------------------- launcher
extern "C" void kernel_launch(void* const* d_in, const int* in_sizes, int n_in,
                              void* d_out, int out_size, void* d_ws, size_t ws_size,
                              hipStream_t stream) {
  const float* x     = (const float*)d_in[0];
  const float* qkv_w = (const float*)d_in[1];
  const float* qkv_b = (const float*)d_in[2];
  const float* out_w = (const float*)d_in[3];
  const float* out_b = (const float*)d_in[4];
  float* out = (float*)d_out;

  char* w = (char*)d_ws;
  bf16* xb    = (bf16*)w; w += (size_t)MT * DM * 2;
  bf16* wqkv  = (bf16*)w; w += (size_t)QKVN * DM * 2;
  bf16* wout  = (bf16*)w; w += (size_t)DM * DM * 2;
  bf16* Qw    = (bf16*)w; w += (size_t)MT * DM * 2;        // [bh][n][d], scaled 0.125*log2e
  bf16* Kw    = (bf16*)w; w += (size_t)MT * DM * 2;        // [bh][n][d]
  bf16* Vtw   = (bf16*)w; w += (size_t)MT * DM * 2;        // [bh][d][n]
  bf16* attnV = (bf16*)w; w += (size_t)MT * DM * 2;        // [m][768]

  const int tot4 = NX4 + NW14 + NW24;
  cvt_all<<<dim3((tot4 + 255) / 256), 256, 0, stream>>>(x, qkv_w, out_w, xb, wqkv, wout);

  gemm_bt<0><<<dim3((QKVN / 128) * (MT / 128)), 256, 0, stream>>>(
      xb, wqkv, qkv_b, Qw, Kw, Vtw, nullptr, MT, QKVN, DM);

  flash_attn<<<dim3(SEQ / 128, 2 * NH), 256, 0, stream>>>(Qw, Kw, Vtw, attnV);

  gemm_bt<1><<<dim3((DM / 128) * (MT / 128)), 256, 0, stream>>>(
      attnV, wout, out_b, nullptr, nullptr, nullptr, out, MT, DM, DM);
}

// Round 12
// 282.466 us; speedup vs baseline: 1.0806x; 1.0638x over previous
//
#include <hip/hip_runtime.h>
#include <cstdint>

#define SEQ 4096
#define NH 12
#define DH 64
#define DM 768
#define MT 8192      // B*SEQ
#define QKVN 2304    // 3*DM

typedef __bf16 bf16;
typedef __attribute__((ext_vector_type(8))) __bf16 bf16x8;
typedef __attribute__((ext_vector_type(4))) __bf16 bf16x4;
typedef __attribute__((ext_vector_type(2))) __bf16 bf16x2;
typedef __attribute__((ext_vector_type(4))) float f32x4;
typedef __attribute__((ext_vector_type(16))) float f32x16;
typedef __attribute__((ext_vector_type(2))) int int2v;

// async global->LDS, 16B per lane. LDS dest is wave-uniform base + lane*16.
__device__ __forceinline__ void async_ld16(const void* g, void* lds) {
  __builtin_amdgcn_global_load_lds(
      (__attribute__((address_space(1))) void*)(void*)g,
      (__attribute__((address_space(3))) void*)lds, 16, 0, 0);
}

// Schraudolph-style exp2 emitting BF16 BITS directly, two elements packed.
// bf16(2^s) bits ~= (int)(s*128 + 16251.5); +-3.5% rel, softmax-ratio cancels
// the common mode. Integer/VALU only — never touches the trans pipe.
__device__ __forceinline__ int pexp2_pair(float s0, float s1) {
  int j0 = (int)__builtin_fmaf(s0, 128.0f, 16251.5f);
  int j1 = (int)__builtin_fmaf(s1, 128.0f, 16251.5f);
  return j0 | (j1 << 16);
}

// (a,b) -> a' = {a.lo32, b.lo32}, b' = {a.hi32, b.hi32}
__device__ __forceinline__ void lane32_swap(int& a, int& b) {
#if __has_builtin(__builtin_amdgcn_permlane32_swap)
  int2v r = __builtin_amdgcn_permlane32_swap(a, b, false, false);
  a = r.x; b = r.y;
#else
  int hi = (threadIdx.x & 63) >> 5;
  int ra = __shfl_xor(a, 32, 64), rb = __shfl_xor(b, 32, 64);
  int na = hi ? rb : a;
  int nb = hi ? b : ra;
  a = na; b = nb;
#endif
}

// ---------------------------------------------------------------- converts (merged)
#define NX4  (MT * DM / 4)
#define NW14 (QKVN * DM / 4)
#define NW24 (DM * DM / 4)
__global__ void cvt_all(const float* __restrict__ x, const float* __restrict__ w1,
                        const float* __restrict__ w2, bf16* __restrict__ xb,
                        bf16* __restrict__ wb1, bf16* __restrict__ wb2) {
  int i = blockIdx.x * blockDim.x + threadIdx.x;
  const float* src; bf16* dst; int j;
  if (i < NX4) { src = x; dst = xb; j = i; }
  else if (i < NX4 + NW14) { src = w1; dst = wb1; j = i - NX4; }
  else if (i < NX4 + NW14 + NW24) { src = w2; dst = wb2; j = i - NX4 - NW14; }
  else return;
  f32x4 v = ((const f32x4*)src)[j];
  bf16x4 o;
  o.x = (bf16)v.x; o.y = (bf16)v.y; o.z = (bf16)v.z; o.w = (bf16)v.w;
  ((bf16x4*)dst)[j] = o;
}

// ---------------------------------------------------------------- GEMM (B^T)
// C[M,N] = A[M,K] @ Bw[N,K]^T. 128x128 tile, BK=32, 4 waves, 64x64/wave.
// 1-D grid with grouped swizzle (R10-verified: non-flash 162 -> 146.5 us).
// MODE 0: QKV epilogue -> +bias, Q(*0.125*log2e)/K as [bh][n][d]; V^T via LDS -> [bh][d][n]
// MODE 1: out-proj epilogue -> +bias, fp32 row-major [M,N]
template<int MODE>
__global__ __launch_bounds__(256) void gemm_bt(
    const bf16* __restrict__ A, const bf16* __restrict__ Bw,
    const float* __restrict__ bias,
    bf16* __restrict__ outQ, bf16* __restrict__ outK, bf16* __restrict__ outVt,
    float* __restrict__ outF,
    int M, int N, int K)
{
  __shared__ bf16 sA[128 * 32];
  __shared__ bf16 sB[128 * 32];
  __shared__ bf16 sT[MODE == 0 ? 64 * 136 : 1];   // V^T bounce buffer
  const int tid  = threadIdx.x;
  const int wave = tid >> 6;
  const int lane = tid & 63;
  const int l15  = lane & 15;
  const int quad = lane >> 4;

  constexpr int NT = (MODE == 0) ? (QKVN / 128) : (DM / 128);
  const int lin = blockIdx.x;
  const int rem = lin % (NT * 8);
  const int m0 = ((lin / (NT * 8)) * 8 + (rem % 8)) * 128;
  const int n0 = (rem / 8) * 128;

  const int rowbase = (wave >> 1) * 64;
  const int colbase = (wave & 1) * 64;

  f32x4 acc[4][4] = {};

  const int sr = lane >> 2;
  const int sc = (lane & 3) * 8;

  for (int kt = 0; kt < K; kt += 32) {
#pragma unroll
    for (int p = 0; p < 4; ++p) {
      int chunk = p * 4 + wave;
      int r = (chunk & 7) * 16 + sr;
      if (chunk < 8) {
        async_ld16(A + (size_t)(m0 + r) * K + kt + sc, &sA[(chunk & 7) * 512]);
      } else {
        async_ld16(Bw + (size_t)(n0 + r) * K + kt + sc, &sB[(chunk & 7) * 512]);
      }
    }
    __syncthreads();

    bf16x8 af[4], bfr[4];
#pragma unroll
    for (int rt = 0; rt < 4; ++rt)
      af[rt] = *(const bf16x8*)&sA[(rowbase + rt * 16 + l15) * 32 + quad * 8];
#pragma unroll
    for (int ct = 0; ct < 4; ++ct)
      bfr[ct] = *(const bf16x8*)&sB[(colbase + ct * 16 + l15) * 32 + quad * 8];
#pragma unroll
    for (int rt = 0; rt < 4; ++rt)
#pragma unroll
      for (int ct = 0; ct < 4; ++ct)
        acc[rt][ct] = __builtin_amdgcn_mfma_f32_16x16x32_bf16(af[rt], bfr[ct], acc[rt][ct], 0, 0, 0);
    __syncthreads();
  }

  if (MODE == 0) {
    const int g = n0 / DM;                       // uniform per block (0=q,1=k,2=v)
    if (g < 2) {
      const float qscale = 0.125f * 1.4426950408889634f;  // fold /8 and log2(e) for exp2
#pragma unroll
      for (int ct = 0; ct < 4; ++ct) {
        int j = n0 + colbase + ct * 16 + l15;
        float bj = bias[j];
        int f = j % DM;
        int h = f >> 6, d = f & 63;
#pragma unroll
        for (int rt = 0; rt < 4; ++rt) {
          int mrow = m0 + rowbase + rt * 16 + quad * 4;
#pragma unroll
          for (int r = 0; r < 4; ++r) {
            float v = acc[rt][ct][r] + bj;
            int m = mrow + r;
            int b = m >> 12, n = m & 4095;
            int bh = b * NH + h;
            if (g == 0) outQ[((size_t)bh * SEQ + n) * DH + d] = (bf16)(v * qscale);
            else        outK[((size_t)bh * SEQ + n) * DH + d] = (bf16)v;
          }
        }
      }
    } else {
      // V block: bounce through LDS, store V^T coalesced along n
      const int f0 = n0 - 2 * DM;                // d-col base in [0,768)
      const int b = m0 >> 12, n0m = m0 & 4095;
#pragma unroll
      for (int p = 0; p < 2; ++p) {
        __syncthreads();
        if (colbase == p * 64) {
#pragma unroll
          for (int ct = 0; ct < 4; ++ct) {
            int jl = ct * 16 + l15;              // 0..63 within half
            float bj = bias[n0 + p * 64 + jl];
#pragma unroll
            for (int rt = 0; rt < 4; ++rt) {
              int ml = rowbase + rt * 16 + quad * 4;
#pragma unroll
              for (int r = 0; r < 4; ++r)
                sT[jl * 136 + ml + r] = (bf16)(acc[rt][ct][r] + bj);
            }
          }
        }
        __syncthreads();
#pragma unroll
        for (int p2 = 0; p2 < 4; ++p2) {
          int slot = p2 * 256 + tid;             // 64 j-rows x 16 m-chunks
          int jr = slot >> 4, mc = (slot & 15) * 8;
          int fj = f0 + p * 64 + jr;
          int h = fj >> 6, d = fj & 63;
          *(bf16x8*)&outVt[((size_t)(b * NH + h) * DH + d) * SEQ + n0m + mc] =
              *(const bf16x8*)&sT[jr * 136 + mc];
        }
      }
    }
  } else {
#pragma unroll
    for (int ct = 0; ct < 4; ++ct) {
      int j = n0 + colbase + ct * 16 + l15;
      float bj = bias[j];
#pragma unroll
      for (int rt = 0; rt < 4; ++rt) {
        int mrow = m0 + rowbase + rt * 16 + quad * 4;
#pragma unroll
        for (int r = 0; r < 4; ++r)
          outF[(size_t)(mrow + r) * N + j] = acc[rt][ct][r] + bj;
      }
    }
  }
}

// ---------------------------------------------------------------- flash attention v12
// = R9 flash VERBATIM (proven 125 us: VGPR 84, occupancy 27.3%, MfmaUtil 46.5%).
// R10/R11 post-mortems: hoisting the second S chain (any variant) adds >=16 live
// regs, crosses the ~2-waves/SIMD unified-file cliff (occ 27->17.5%), and loses
// 27-33 us. Per-kb ordering with ONE s live is the register/ILP optimum here.
__global__ __launch_bounds__(256) void flash_attn(
    const bf16* __restrict__ Q, const bf16* __restrict__ Kg,
    const bf16* __restrict__ Vt, bf16* __restrict__ Oout)
{
  __shared__ bf16 sK[2][64 * 64];    // [key][d], granule-swizzled
  __shared__ bf16 sV[2][64 * 64];    // [d][key], granule-swizzled

  const int tid  = threadIdx.x;
  const int wave = tid >> 6;
  const int lane = tid & 63;
  const int l31  = lane & 31;
  const int hi   = lane >> 5;
  const int bh = blockIdx.y;
  const int q0w = blockIdx.x * 128 + wave * 32;

  const bf16* Qb = Q  + (size_t)bh * SEQ * DH;
  const bf16* Kb = Kg + (size_t)bh * SEQ * DH;
  const bf16* Vb = Vt + (size_t)bh * DH * SEQ;

  const int srow = lane >> 3;        // staging: row within 8-row chunk
  const int spg  = lane & 7;         // staging: physical granule (16B) within row

  // Q B-fragments; 16 VGPRs, live whole kernel
  bf16x8 qf[4];
#pragma unroll
  for (int dc = 0; dc < 4; ++dc)
    qf[dc] = *(const bf16x8*)&Qb[(size_t)(q0w + l31) * DH + dc * 16 + hi * 8];

  // ones B-fragment for row-sum MFMA
  bf16x8 ones1;
#pragma unroll
  for (int j = 0; j < 8; ++j) ones1[j] = (bf16)1.0f;

  f32x16 o0 = {}, o1 = {}, o2 = {};
  f32x16 zc = {};                    // persistent zero C operand (never written)

  // hoisted LDS element offsets (kt-invariant); 2-D swizzle key
  const int keyk = (l31 & 7) ^ (((l31 >> 3) & 3) << 1);
  int kOff[4], vOff[4];
#pragma unroll
  for (int dc = 0; dc < 4; ++dc)
    kOff[dc] = l31 * 64 + (((dc * 2 + hi) ^ keyk) * 8);
#pragma unroll
  for (int k4 = 0; k4 < 4; ++k4)     // k4 = kb*2+kc
    vOff[k4] = l31 * 64 + (((k4 * 2 + hi) ^ keyk) * 8);

  auto stage = [&](int kt, int buf) {
#pragma unroll
    for (int j = 0; j < 2; ++j) {
      int r0 = wave * 16 + j * 8;
      int row = r0 + srow;
      int lg = spg ^ (row & 7) ^ (((row >> 3) & 3) << 1);
      async_ld16(Kb + (size_t)(kt + row) * DH + lg * 8, &sK[buf][r0 * 64]);
      async_ld16(Vb + (size_t)row * SEQ + kt + lg * 8, &sV[buf][r0 * 64]);
    }
  };

  auto compute = [&](const bf16* sKp, const bf16* sVp) {
#pragma unroll
    for (int kb = 0; kb < 2; ++kb) {
      f32x16 s;
      {
        bf16x8 kf = *(const bf16x8*)&sKp[kOff[0] + kb * 2048];
        s = __builtin_amdgcn_mfma_f32_32x32x16_bf16(kf, qf[0], zc, 0, 0, 0);
      }
#pragma unroll
      for (int dc = 1; dc < 4; ++dc) {
        bf16x8 kf = *(const bf16x8*)&sKp[kOff[dc] + kb * 2048];
        s = __builtin_amdgcn_mfma_f32_32x32x16_bf16(kf, qf[dc], s, 0, 0, 0);
      }
#pragma unroll
      for (int kc = 0; kc < 2; ++kc) {
        int g0a = pexp2_pair(s[8 * kc + 0], s[8 * kc + 1]);
        int g0b = pexp2_pair(s[8 * kc + 2], s[8 * kc + 3]);
        int g1a = pexp2_pair(s[8 * kc + 4], s[8 * kc + 5]);
        int g1b = pexp2_pair(s[8 * kc + 6], s[8 * kc + 7]);
        lane32_swap(g0a, g1a);
        lane32_swap(g0b, g1b);
        union { int i[4]; bf16x8 v; } Af;
        Af.i[0] = g0a; Af.i[1] = g0b; Af.i[2] = g1a; Af.i[3] = g1b;
        bf16x8 vf0 = *(const bf16x8*)&sVp[vOff[kb * 2 + kc]];
        bf16x8 vf1 = *(const bf16x8*)&sVp[vOff[kb * 2 + kc] + 2048];
        o0 = __builtin_amdgcn_mfma_f32_32x32x16_bf16(Af.v, vf0, o0, 0, 0, 0);
        o1 = __builtin_amdgcn_mfma_f32_32x32x16_bf16(Af.v, vf1, o1, 0, 0, 0);
        o2 = __builtin_amdgcn_mfma_f32_32x32x16_bf16(Af.v, ones1, o2, 0, 0, 0);
      }
    }
  };

  stage(0, 0);
  __syncthreads();

  for (int kt = 0; kt < SEQ; kt += 128) {
    if (kt + 64 < SEQ) stage(kt + 64, 1);
    compute(sK[0], sV[0]);
    __syncthreads();
    if (kt + 128 < SEQ) stage(kt + 128, 0);
    compute(sK[1], sV[1]);
    __syncthreads();
  }

  // epilogue: o2[i] is the softmax denominator for exactly o0[i]/o1[i]'s row
  const int bg = bh / NH, h = bh % NH;
#pragma unroll
  for (int i = 0; i < 16; ++i) {
    int ql = 8 * (i >> 2) + (i & 3) + 4 * hi;
    float inv = 1.0f / o2[i];
    size_t base = (size_t)(bg * SEQ + q0w + ql) * DM + h * DH;
    Oout[base + l31]      = (bf16)(o0[i] * inv);
    Oout[base + 32 + l31] = (bf16)(o1[i] * inv);
  }
}

// ---------------------------------------------------------------- launcher
extern "C" void kernel_launch(void* const* d_in, const int* in_sizes, int n_in,
                              void* d_out, int out_size, void* d_ws, size_t ws_size,
                              hipStream_t stream) {
  const float* x     = (const float*)d_in[0];
  const float* qkv_w = (const float*)d_in[1];
  const float* qkv_b = (const float*)d_in[2];
  const float* out_w = (const float*)d_in[3];
  const float* out_b = (const float*)d_in[4];
  float* out = (float*)d_out;

  char* w = (char*)d_ws;
  bf16* xb    = (bf16*)w; w += (size_t)MT * DM * 2;
  bf16* wqkv  = (bf16*)w; w += (size_t)QKVN * DM * 2;
  bf16* wout  = (bf16*)w; w += (size_t)DM * DM * 2;
  bf16* Qw    = (bf16*)w; w += (size_t)MT * DM * 2;        // [bh][n][d], scaled 0.125*log2e
  bf16* Kw    = (bf16*)w; w += (size_t)MT * DM * 2;        // [bh][n][d]
  bf16* Vtw   = (bf16*)w; w += (size_t)MT * DM * 2;        // [bh][d][n]
  bf16* attnV = (bf16*)w; w += (size_t)MT * DM * 2;        // [m][768]

  const int tot4 = NX4 + NW14 + NW24;
  cvt_all<<<dim3((tot4 + 255) / 256), 256, 0, stream>>>(x, qkv_w, out_w, xb, wqkv, wout);

  gemm_bt<0><<<dim3((QKVN / 128) * (MT / 128)), 256, 0, stream>>>(
      xb, wqkv, qkv_b, Qw, Kw, Vtw, nullptr, MT, QKVN, DM);

  flash_attn<<<dim3(SEQ / 128, 2 * NH), 256, 0, stream>>>(Qw, Kw, Vtw, attnV);

  gemm_bt<1><<<dim3((DM / 128) * (MT / 128)), 256, 0, stream>>>(
      attnV, wout, out_b, nullptr, nullptr, nullptr, out, MT, DM, DM);
}